// Round 1
// baseline (103.697 us; speedup 1.0000x reference)
//
#include <hip/hip_runtime.h>
#include <math.h>

#define N_S 2
#define N_V 4
#define DQ  64
#define HH  256
#define WW  320
#define DPT 16   // depths per thread

// ws layout (floats): [N_S*N_V][12]  = A(9) + b(3) per (n,v)
//                     then [N_S][9]  = inv(Kd) per n
#define WS_IK_OFF (N_S * N_V * 12)

__global__ void setup_kernel(const float* __restrict__ Kd,
                             const float* __restrict__ Ed,
                             const float* __restrict__ Ks,
                             const float* __restrict__ Es,
                             float* __restrict__ ws) {
    int i = threadIdx.x;
    if (i >= N_S * N_V) return;
    int n = i / N_V;
    int v = i % N_V;

    // --- inv(Ed): Ed is rigid [R|t; 0 0 0 1] -> inv = [R^T | -R^T t]
    const float* E = Ed + n * 16;
    float Ri[3][3], ti[3];
    for (int r = 0; r < 3; ++r)
        for (int c = 0; c < 3; ++c)
            Ri[r][c] = E[c * 4 + r];          // R^T
    for (int r = 0; r < 3; ++r)
        ti[r] = -(Ri[r][0] * E[3] + Ri[r][1] * E[7] + Ri[r][2] * E[11]);

    // --- T = Es(n,v) @ inv(Ed); keep R,t parts
    const float* S = Es + (n * N_V + v) * 16;
    float Tr[3][3], Tt[3];
    for (int r = 0; r < 3; ++r) {
        for (int c = 0; c < 3; ++c)
            Tr[r][c] = S[r*4+0]*Ri[0][c] + S[r*4+1]*Ri[1][c] + S[r*4+2]*Ri[2][c];
        Tt[r] = S[r*4+0]*ti[0] + S[r*4+1]*ti[1] + S[r*4+2]*ti[2] + S[r*4+3];
    }

    // --- A = Ksrc @ Tr ; b = Ksrc @ Tt
    const float* Kv = Ks + (n * N_V + v) * 9;
    float* dst = ws + i * 12;
    for (int r = 0; r < 3; ++r) {
        for (int c = 0; c < 3; ++c)
            dst[r*3+c] = Kv[r*3+0]*Tr[0][c] + Kv[r*3+1]*Tr[1][c] + Kv[r*3+2]*Tr[2][c];
        dst[9+r] = Kv[r*3+0]*Tt[0] + Kv[r*3+1]*Tt[1] + Kv[r*3+2]*Tt[2];
    }

    // --- inv(Kd) per n (adjugate / det)
    if (v == 0) {
        const float* Km = Kd + n * 9;
        float a=Km[0],b=Km[1],c=Km[2],d=Km[3],e=Km[4],f=Km[5],g=Km[6],h=Km[7],k=Km[8];
        float det = a*(e*k - f*h) - b*(d*k - f*g) + c*(d*h - e*g);
        float inv = 1.0f / det;
        float* ik = ws + WS_IK_OFF + n * 9;
        ik[0] =  (e*k - f*h) * inv;
        ik[1] = -(b*k - c*h) * inv;
        ik[2] =  (b*f - c*e) * inv;
        ik[3] = -(d*k - f*g) * inv;
        ik[4] =  (a*k - c*g) * inv;
        ik[5] = -(a*f - c*d) * inv;
        ik[6] =  (d*h - e*g) * inv;
        ik[7] = -(a*h - b*g) * inv;
        ik[8] =  (a*e - b*d) * inv;
    }
}

__global__ __launch_bounds__(256) void warp_kernel(const float* __restrict__ ws,
                                                   float* __restrict__ out) {
    const int HW = HH * WW;
    long long idx = (long long)blockIdx.x * blockDim.x + threadIdx.x;
    const long long total = (long long)N_S * N_V * (DQ / DPT) * HW;
    if (idx >= total) return;

    int w  = (int)(idx % WW);
    int h  = (int)((idx / WW) % HH);
    int dc = (int)((idx / HW) % (DQ / DPT));
    int nv = (int)(idx / ((long long)HW * (DQ / DPT)));   // n*N_V + v
    int n  = nv / N_V;

    const float* ab = ws + nv * 12;
    float A00=ab[0],A01=ab[1],A02=ab[2];
    float A10=ab[3],A11=ab[4],A12=ab[5];
    float A20=ab[6],A21=ab[7],A22=ab[8];
    float b0=ab[9], b1=ab[10], b2=ab[11];
    const float* ik = ws + WS_IK_OFF + n * 9;

    float X = (float)w, Y = (float)h;
    float rx = ik[0]*X + ik[1]*Y + ik[2];
    float ry = ik[3]*X + ik[4]*Y + ik[5];
    float rz = ik[6]*X + ik[7]*Y + ik[8];

    float bx = A00*rx + A01*ry + A02*rz;
    float by = A10*rx + A11*ry + A12*rz;
    float bz = A20*rx + A21*ry + A22*rz;

    size_t pix    = (size_t)h * WW + w;
    size_t xybase = ((size_t)nv * DQ + (size_t)dc * DPT) * HW + pix;
    float2* __restrict__ xyout = (float2*)out;
    float*  __restrict__ mout  = out + (size_t)N_S * N_V * DQ * HW * 2;

    const float step = (float)(9.5 / 63.0);   // linspace(0.5, 10, 64) step
    int d0 = dc * DPT;
    #pragma unroll
    for (int j = 0; j < DPT; ++j) {
        float depth = 0.5f + (float)(d0 + j) * step;
        float px = depth * bx + b0;
        float py = depth * by + b1;
        float pz = depth * bz + b2;
        float zs = (fabsf(pz) < 1e-8f) ? 1e-8f : pz;
        float x = px / zs;
        float y = py / zs;
        float m = (x >= 0.0f && x <= (float)(WW - 1) &&
                   y >= 0.0f && y <= (float)(HH - 1) &&
                   pz > 0.0f) ? 1.0f : 0.0f;
        size_t o = xybase + (size_t)j * HW;
        xyout[o] = make_float2(x, y);
        mout[o]  = m;
    }
}

extern "C" void kernel_launch(void* const* d_in, const int* in_sizes, int n_in,
                              void* d_out, int out_size, void* d_ws, size_t ws_size,
                              hipStream_t stream) {
    const float* Kd = (const float*)d_in[0];   // dst_intrinsics (N,1,3,3)
    const float* Ed = (const float*)d_in[1];   // dst_extrinsics (N,1,4,4)
    const float* Ks = (const float*)d_in[2];   // src_intrinsics (N,V,3,3)
    const float* Es = (const float*)d_in[3];   // src_extrinsics (N,V,4,4)
    float* ws = (float*)d_ws;

    hipLaunchKernelGGL(setup_kernel, dim3(1), dim3(64), 0, stream, Kd, Ed, Ks, Es, ws);

    long long total = (long long)N_S * N_V * (DQ / DPT) * HH * WW;
    int blocks = (int)((total + 255) / 256);
    hipLaunchKernelGGL(warp_kernel, dim3(blocks), dim3(256), 0, stream,
                       (const float*)ws, (float*)d_out);
}

// Round 2
// 94.948 us; speedup vs baseline: 1.0921x; 1.0921x over previous
//
#include <hip/hip_runtime.h>
#include <math.h>

#define N_S 2
#define N_V 4
#define DQ  64
#define HH  256
#define WW  320
#define WW2 (WW / 2)
#define DPT 16
#define NDC (DQ / DPT)   // depth chunks = 4

typedef float f32x4 __attribute__((ext_vector_type(4)));
typedef float f32x2 __attribute__((ext_vector_type(2)));

__global__ __launch_bounds__(256) void fused_warp_kernel(
    const float* __restrict__ Kd,
    const float* __restrict__ Ed,
    const float* __restrict__ Ks,
    const float* __restrict__ Es,
    float* __restrict__ out)
{
    const int HW = HH * WW;
    int idx = blockIdx.x * 256 + threadIdx.x;

    int w2 = idx % WW2;
    int tt = idx / WW2;
    int h  = tt % HH;
    tt /= HH;
    int dc = tt % NDC;
    int nv = tt / NDC;          // n*N_V + v  (uniform per block)
    int n  = nv >> 2;           // N_V == 4

    // ---- per-(n,v) camera algebra (tiny, fully cached) ----
    // inv(Ed): rigid [R|t] -> [R^T | -R^T t]
    const float* E = Ed + n * 16;
    float Ri[3][3], ti[3];
    #pragma unroll
    for (int r = 0; r < 3; ++r)
        #pragma unroll
        for (int c = 0; c < 3; ++c)
            Ri[r][c] = E[c * 4 + r];
    #pragma unroll
    for (int r = 0; r < 3; ++r)
        ti[r] = -(Ri[r][0] * E[3] + Ri[r][1] * E[7] + Ri[r][2] * E[11]);

    // T = Es @ inv(Ed)
    const float* S = Es + nv * 16;
    float Tr[3][3], Tt[3];
    #pragma unroll
    for (int r = 0; r < 3; ++r) {
        #pragma unroll
        for (int c = 0; c < 3; ++c)
            Tr[r][c] = S[r*4+0]*Ri[0][c] + S[r*4+1]*Ri[1][c] + S[r*4+2]*Ri[2][c];
        Tt[r] = S[r*4+0]*ti[0] + S[r*4+1]*ti[1] + S[r*4+2]*ti[2] + S[r*4+3];
    }

    // A = Ksrc @ Tr ; b = Ksrc @ Tt
    const float* Kv = Ks + nv * 9;
    float A00,A01,A02,A10,A11,A12,A20,A21,A22,b0,b1,b2;
    {
        float Am[3][3], bm[3];
        #pragma unroll
        for (int r = 0; r < 3; ++r) {
            #pragma unroll
            for (int c = 0; c < 3; ++c)
                Am[r][c] = Kv[r*3+0]*Tr[0][c] + Kv[r*3+1]*Tr[1][c] + Kv[r*3+2]*Tr[2][c];
            bm[r] = Kv[r*3+0]*Tt[0] + Kv[r*3+1]*Tt[1] + Kv[r*3+2]*Tt[2];
        }
        A00=Am[0][0];A01=Am[0][1];A02=Am[0][2];
        A10=Am[1][0];A11=Am[1][1];A12=Am[1][2];
        A20=Am[2][0];A21=Am[2][1];A22=Am[2][2];
        b0=bm[0];b1=bm[1];b2=bm[2];
    }

    // inv(Kd) via adjugate/det
    float ik0,ik1,ik2,ik3,ik4,ik5,ik6,ik7,ik8;
    {
        const float* Km = Kd + n * 9;
        float a=Km[0],b=Km[1],c=Km[2],d=Km[3],e=Km[4],f=Km[5],g=Km[6],hh=Km[7],k=Km[8];
        float det = a*(e*k - f*hh) - b*(d*k - f*g) + c*(d*hh - e*g);
        float inv = 1.0f / det;
        ik0 =  (e*k - f*hh) * inv;
        ik1 = -(b*k - c*hh) * inv;
        ik2 =  (b*f - c*e) * inv;
        ik3 = -(d*k - f*g) * inv;
        ik4 =  (a*k - c*g) * inv;
        ik5 = -(a*f - c*d) * inv;
        ik6 =  (d*hh - e*g) * inv;
        ik7 = -(a*hh - b*g) * inv;
        ik8 =  (a*e - b*d) * inv;
    }

    // ---- per-pixel-pair ray + base (independent per pixel, matches ref) ----
    float X0 = (float)(2 * w2), X1 = X0 + 1.0f, Y = (float)h;

    float rx0 = ik0*X0 + ik1*Y + ik2;
    float ry0 = ik3*X0 + ik4*Y + ik5;
    float rz0 = ik6*X0 + ik7*Y + ik8;
    float rx1 = ik0*X1 + ik1*Y + ik2;
    float ry1 = ik3*X1 + ik4*Y + ik5;
    float rz1 = ik6*X1 + ik7*Y + ik8;

    float bx0 = A00*rx0 + A01*ry0 + A02*rz0;
    float by0 = A10*rx0 + A11*ry0 + A12*rz0;
    float bz0 = A20*rx0 + A21*ry0 + A22*rz0;
    float bx1 = A00*rx1 + A01*ry1 + A02*rz1;
    float by1 = A10*rx1 + A11*ry1 + A12*rz1;
    float bz1 = A20*rx1 + A21*ry1 + A22*rz1;

    size_t pixbase = ((size_t)nv * DQ + (size_t)dc * DPT) * HW
                   + (size_t)h * WW + (size_t)(2 * w2);
    float* __restrict__ mout = out + (size_t)N_S * N_V * DQ * HW * 2;

    const float step = (float)(9.5 / 63.0);   // linspace(0.5,10,64) step
    int d0 = dc * DPT;

    #pragma unroll
    for (int j = 0; j < DPT; ++j) {
        float depth = 0.5f + (float)(d0 + j) * step;

        float px0 = depth*bx0 + b0, py0 = depth*by0 + b1, pz0 = depth*bz0 + b2;
        float px1 = depth*bx1 + b0, py1 = depth*by1 + b1, pz1 = depth*bz1 + b2;

        float zs0 = (fabsf(pz0) < 1e-8f) ? 1e-8f : pz0;
        float zs1 = (fabsf(pz1) < 1e-8f) ? 1e-8f : pz1;

        float x0 = px0 / zs0, y0 = py0 / zs0;
        float x1 = px1 / zs1, y1 = py1 / zs1;

        float m0 = (x0 >= 0.0f && x0 <= (float)(WW-1) &&
                    y0 >= 0.0f && y0 <= (float)(HH-1) && pz0 > 0.0f) ? 1.0f : 0.0f;
        float m1 = (x1 >= 0.0f && x1 <= (float)(WW-1) &&
                    y1 >= 0.0f && y1 <= (float)(HH-1) && pz1 > 0.0f) ? 1.0f : 0.0f;

        size_t p = pixbase + (size_t)j * HW;

        f32x4 xyv; xyv.x = x0; xyv.y = y0; xyv.z = x1; xyv.w = y1;
        __builtin_nontemporal_store(xyv, (f32x4*)(out + 2 * p));
        f32x2 mv; mv.x = m0; mv.y = m1;
        __builtin_nontemporal_store(mv, (f32x2*)(mout + p));
    }
}

extern "C" void kernel_launch(void* const* d_in, const int* in_sizes, int n_in,
                              void* d_out, int out_size, void* d_ws, size_t ws_size,
                              hipStream_t stream) {
    const float* Kd = (const float*)d_in[0];   // (N,1,3,3)
    const float* Ed = (const float*)d_in[1];   // (N,1,4,4)
    const float* Ks = (const float*)d_in[2];   // (N,V,3,3)
    const float* Es = (const float*)d_in[3];   // (N,V,4,4)

    const long long total = (long long)N_S * N_V * NDC * HH * WW2;  // 1,310,720
    int blocks = (int)((total + 255) / 256);                         // 5120
    hipLaunchKernelGGL(fused_warp_kernel, dim3(blocks), dim3(256), 0, stream,
                       Kd, Ed, Ks, Es, (float*)d_out);
}